// Round 9
// baseline (222.787 us; speedup 1.0000x reference)
//
#include <hip/hip_runtime.h>
#include <hip/hip_fp16.h>

// GCN 2-layer: out = A_hat @ relu(A_hat @ (X W1) + b1) W2 + b2
// A_hat = D^-1/2 (A+I) D^-1/2.
// R21 (on R20's 170.8 us; R20's bucket||gemm overlap CONFIRMED, -5 us):
//   statsfill's count pass (6.4 MB ebuf re-read + 1.6M LDS atomics, only
//   to recover per-row degree) deleted. Degrees now accumulated in
//   bucket_gemm via fire-and-forget global atomicAdd on deg[] (200 KB,
//   L2-resident; R17 proved the COUNT side cheap -- it was the value-
//   returning scatter FILL that exploded there). statsfill derives
//   rpf/dinv from deg directly (256 loads + LDS scan). Fill pass over
//   ebuf (LDS pos ranking) unchanged.
// Everything else identical to R20 (mega-kernel bucket||gemm-unscaled,
// statsfill scales xwh1 in place, R18 aggregate core, ushort csr,
// fused gemm2 in gather1, nt out-stores).

#define P1_EDGES 4096
#define BSTRIDE 16384   // ebuf slots per bucket (fixed stride), ~2x avg fill

typedef float vfloat4 __attribute__((ext_vector_type(4)));  // native vec for nt-store

// ---- mega kernel: blocks [0,nbP1) = edge bucketing (+deg count); blocks
// [nbP1, ...) = xw1 = fp16(X @ W1) UNSCALED (16 waves, 4 rows/wave) ----
__global__ void bucket_gemm_kernel(const int* __restrict__ src, const int* __restrict__ dst,
                                   unsigned* __restrict__ cursor, unsigned* __restrict__ deg,
                                   unsigned* __restrict__ ebuf,
                                   const float4* __restrict__ X4, const float* __restrict__ W,
                                   __half* __restrict__ Yh,
                                   int e, int B, int n, int nbP1) {
    __shared__ unsigned hist[256];
    __shared__ unsigned base[256];
    __shared__ float4 Ws[64][16];
    int bid = blockIdx.x;
    if (bid < nbP1) {
        // ---- bucket branch: scatter edges by dst>>8; ebuf[slot]=dst<<16|src ----
        for (int i = threadIdx.x; i < B; i += 1024) hist[i] = 0;
        __syncthreads();
        int e0 = bid * P1_EDGES;
        int tbase = e0 + (int)threadIdx.x * 4;
        int4 sv = make_int4(0, 0, 0, 0), dv = make_int4(0, 0, 0, 0);
        if (tbase + 3 < e) {                       // vectorized 16B edge reads
            sv = ((const int4*)(src + e0))[threadIdx.x];
            dv = ((const int4*)(dst + e0))[threadIdx.x];
        } else {                                   // tail block only
            if (tbase + 0 < e) { sv.x = src[tbase + 0]; dv.x = dst[tbase + 0]; }
            if (tbase + 1 < e) { sv.y = src[tbase + 1]; dv.y = dst[tbase + 1]; }
            if (tbase + 2 < e) { sv.z = src[tbase + 2]; dv.z = dst[tbase + 2]; }
        }
        unsigned bk[4], rk[4], pk[4];
        bool vk[4];
#pragma unroll
        for (int k = 0; k < 4; ++k) {
            int t = tbase + k;
            vk[k] = (t < e);
            bk[k] = 0; rk[k] = 0; pk[k] = 0;
            if (vk[k]) {
                unsigned s = (unsigned)(k == 0 ? sv.x : k == 1 ? sv.y : k == 2 ? sv.z : sv.w);
                unsigned d = (unsigned)(k == 0 ? dv.x : k == 1 ? dv.y : k == 2 ? dv.z : dv.w);
                unsigned b = d >> 8;
                bk[k] = b;
                rk[k] = atomicAdd(&hist[b], 1u);     // rank within (block,bucket)
                pk[k] = (d << 16) | s;               // n < 2^16: both fit
                atomicAdd(&deg[d], 1u);              // fire-and-forget degree count
            }
        }
        __syncthreads();
        for (int i = threadIdx.x; i < B; i += 1024)
            base[i] = hist[i] ? atomicAdd(&cursor[i], hist[i]) : 0u;
        __syncthreads();
#pragma unroll
        for (int k = 0; k < 4; ++k)
            if (vk[k]) {
                unsigned slot = base[bk[k]] + rk[k];
                if (slot < (unsigned)BSTRIDE)                  // overflow drop-guard
                    ebuf[(size_t)bk[k] * BSTRIDE + slot] = pk[k];
            }
    } else {
        // ---- gemm branch: Yh[row] = fp16(X[row] @ W) (no prescale) ----
        for (int i = threadIdx.x; i < 64 * 16; i += 1024)
            Ws[i >> 4][i & 15] = ((const float4*)W)[i];
        __syncthreads();
        int lane = threadIdx.x & 63;
        int l = lane & 15;
        int gbase = lane & 48;
        int wid = (bid - nbP1) * 16 + (threadIdx.x >> 6);
        int row = wid * 4 + (lane >> 4);
        if (row >= n) return;
        float4 xv = X4[(size_t)row * 16 + l];
        float4 acc = make_float4(0.f, 0.f, 0.f, 0.f);
#pragma unroll
        for (int k = 0; k < 64; ++k) {
            float comp = (k & 3) == 0 ? xv.x : (k & 3) == 1 ? xv.y : (k & 3) == 2 ? xv.z : xv.w;
            float a = __shfl(comp, gbase + (k >> 2));
            float4 w = Ws[k][l];
            acc.x = fmaf(a, w.x, acc.x); acc.y = fmaf(a, w.y, acc.y);
            acc.z = fmaf(a, w.z, acc.z); acc.w = fmaf(a, w.w, acc.w);
        }
        __half2 h0 = __floats2half2_rn(acc.x, acc.y);
        __half2 h1 = __floats2half2_rn(acc.z, acc.w);
        uint2 o;
        o.x = *(const unsigned*)&h0;
        o.y = *(const unsigned*)&h1;
        *(uint2*)(Yh + (size_t)row * 64 + 4 * l) = o;
    }
}

// ---- fused per-bucket stats + fill + xwh1 scale. Phase 0: in-block scan
// of cursor -> bstart (fence-free). Then: deg-based window scan -> rpf ->
// scale xwh1 window rows by dinv (in place) -> single ebuf pass ->
// csr[slot] = src (ushort) ----
__global__ void statsfill_kernel(const unsigned* __restrict__ ebuf,
                                 const unsigned* __restrict__ bcnt,
                                 const unsigned* __restrict__ deg,
                                 unsigned* __restrict__ rpf,
                                 __half* __restrict__ xwh1,
                                 unsigned short* __restrict__ csr, int n, int e) {
    __shared__ unsigned pos[256];
    __shared__ unsigned sh[256];
    __shared__ unsigned rpl[256];
    __shared__ float dl[256];
    __shared__ unsigned bs;        // bstart[b] = sum of bcnt[0..b)
    int b = blockIdx.x;
    int w0 = b << 8;
    int wlen = min(w0 + 256, n) - w0;
    // phase 0: global bucket-prefix for this block (cursor words, L2-hot)
    unsigned c0 = 0;
    if (threadIdx.x < 256) { c0 = bcnt[threadIdx.x]; sh[threadIdx.x] = c0; }
    __syncthreads();
    for (int off = 1; off < 256; off <<= 1) {
        unsigned t = 0;
        if (threadIdx.x < 256 && threadIdx.x >= (unsigned)off) t = sh[threadIdx.x - off];
        __syncthreads();
        if (threadIdx.x < 256) sh[threadIdx.x] += t;
        __syncthreads();
    }
    if (threadIdx.x == (unsigned)b) bs = sh[b] - c0;   // exclusive prefix at b
    __syncthreads();
    // phase 1: window scan of deg (replaces the ebuf count pass)
    unsigned dv = 0;
    if (threadIdx.x < 256) {
        if ((int)threadIdx.x < wlen) dv = deg[w0 + threadIdx.x];
        sh[threadIdx.x] = dv;
    }
    __syncthreads();
    for (int off = 1; off < 256; off <<= 1) {
        unsigned t = 0;
        if (threadIdx.x < 256 && threadIdx.x >= (unsigned)off) t = sh[threadIdx.x - off];
        __syncthreads();
        if (threadIdx.x < 256) sh[threadIdx.x] += t;
        __syncthreads();
    }
    if (threadIdx.x < 256) {
        unsigned rp = bs + sh[threadIdx.x] - dv;         // global base + excl scan
        rpl[threadIdx.x] = rp;
        dl[threadIdx.x] = rsqrtf((float)dv + 1.0f);      // +1 self-loop
        if ((int)threadIdx.x < wlen) rpf[w0 + threadIdx.x] = rp;
        pos[threadIdx.x] = 0;                            // for fill ranking
    }
    if (b == (int)gridDim.x - 1 && threadIdx.x == 0) rpf[n] = (unsigned)e;
    __syncthreads();
    // phase S: scale xwh1 rows [w0, w0+wlen) by dinv, in place.
    for (int i = threadIdx.x; i < (wlen << 3); i += 1024) {
        int r = i >> 3, c = i & 7;
        float di = dl[r];
        uint4* p16 = (uint4*)(xwh1 + ((size_t)(w0 + r) << 6)) + c;
        uint4 hv = *p16;
        float2 f0 = __half22float2(*(const __half2*)&hv.x);
        float2 f1 = __half22float2(*(const __half2*)&hv.y);
        float2 f2 = __half22float2(*(const __half2*)&hv.z);
        float2 f3 = __half22float2(*(const __half2*)&hv.w);
        __half2 g0 = __floats2half2_rn(f0.x * di, f0.y * di);
        __half2 g1 = __floats2half2_rn(f1.x * di, f1.y * di);
        __half2 g2 = __floats2half2_rn(f2.x * di, f2.y * di);
        __half2 g3 = __floats2half2_rn(f3.x * di, f3.y * di);
        hv.x = *(const unsigned*)&g0; hv.y = *(const unsigned*)&g1;
        hv.z = *(const unsigned*)&g2; hv.w = *(const unsigned*)&g3;
        *p16 = hv;
    }
    // phase F: fill csr (single ebuf pass, LDS pos ranking)
    unsigned cnt = bcnt[b];
    const unsigned* eb = ebuf + (size_t)b * BSTRIDE;
    for (unsigned j = threadIdx.x; j < cnt; j += 1024) {
        unsigned p = eb[j];                              // L2-hot
        unsigned d = (p >> 16) - w0;
        unsigned r = atomicAdd(&pos[d], 1u);
        csr[rpl[d] + r] = (unsigned short)(p & 0xffffu);
    }
}

// ---- aggregation core (R18 form): 8-lane group per dst row; lane l8 owns
// cols 8*l8..8*l8+7. csr ushort read as uint words (2 edges/word) via lane
// l8 + shfl broadcast; head/tail via 0/1 weights. Rows prescaled. ----
struct f8 { float4 a, b; };

__device__ __forceinline__ f8 aggregate_row8(const __half* __restrict__ xwh,
                                             const unsigned* __restrict__ csrw,
                                             unsigned start, unsigned end,
                                             int row, int l8, int gbase) {
    f8 acc;
    {   // self-loop term: xwh'[row] (prescaled) with weight 1
        uint4 hv = *(const uint4*)(xwh + (size_t)row * 64 + 8 * l8);
        float2 f0 = __half22float2(*(const __half2*)&hv.x);
        float2 f1 = __half22float2(*(const __half2*)&hv.y);
        float2 f2 = __half22float2(*(const __half2*)&hv.z);
        float2 f3 = __half22float2(*(const __half2*)&hv.w);
        acc.a = make_float4(f0.x, f0.y, f1.x, f1.y);
        acc.b = make_float4(f2.x, f2.y, f3.x, f3.y);
    }
    unsigned wb = start >> 1;                        // first csr word
    unsigned jw = wb + (unsigned)l8;
    unsigned ed = (jw * 2 < end) ? __builtin_nontemporal_load(&csrw[jw]) : 0u;
    for (unsigned base = wb; base * 2 < end; base += 8) {
        unsigned jn = base + 8 + (unsigned)l8;
        unsigned ed_next = (jn * 2 < end) ? __builtin_nontemporal_load(&csrw[jn]) : 0u;
#pragma unroll
        for (int t = 0; t < 8; ++t) {
            unsigned p = __shfl(ed, gbase + t);
            unsigned i0 = (base + (unsigned)t) * 2;          // edge idx of lo half
            int s0 = (int)(p & 0xffffu);
            int s1 = (int)(p >> 16);
            float w0 = (i0 >= start && i0 < end) ? 1.0f : 0.0f;  // head+tail guard
            float w1 = (i0 + 1 < end) ? 1.0f : 0.0f;             // i0+1 >= start always
            uint4 hv0 = *(const uint4*)(xwh + (size_t)s0 * 64 + 8 * l8);
            uint4 hv1 = *(const uint4*)(xwh + (size_t)s1 * 64 + 8 * l8);
            float2 a0 = __half22float2(*(const __half2*)&hv0.x);
            float2 a1 = __half22float2(*(const __half2*)&hv0.y);
            float2 a2 = __half22float2(*(const __half2*)&hv0.z);
            float2 a3 = __half22float2(*(const __half2*)&hv0.w);
            acc.a.x = fmaf(w0, a0.x, acc.a.x); acc.a.y = fmaf(w0, a0.y, acc.a.y);
            acc.a.z = fmaf(w0, a1.x, acc.a.z); acc.a.w = fmaf(w0, a1.y, acc.a.w);
            acc.b.x = fmaf(w0, a2.x, acc.b.x); acc.b.y = fmaf(w0, a2.y, acc.b.y);
            acc.b.z = fmaf(w0, a3.x, acc.b.z); acc.b.w = fmaf(w0, a3.y, acc.b.w);
            float2 c0 = __half22float2(*(const __half2*)&hv1.x);
            float2 c1 = __half22float2(*(const __half2*)&hv1.y);
            float2 c2 = __half22float2(*(const __half2*)&hv1.z);
            float2 c3 = __half22float2(*(const __half2*)&hv1.w);
            acc.a.x = fmaf(w1, c0.x, acc.a.x); acc.a.y = fmaf(w1, c0.y, acc.a.y);
            acc.a.z = fmaf(w1, c1.x, acc.a.z); acc.a.w = fmaf(w1, c1.y, acc.a.w);
            acc.b.x = fmaf(w1, c2.x, acc.b.x); acc.b.y = fmaf(w1, c2.y, acc.b.y);
            acc.b.z = fmaf(w1, c3.x, acc.b.z); acc.b.w = fmaf(w1, c3.y, acc.b.w);
        }
        ed = ed_next;
    }
    return acc;
}

// ---- gather1 + fused gemm2: h = relu(di*agg + b1) (regs only);
// xwh2' = di * (h @ W2) -> fp16. di from row_ptr (deg = end-start). ----
__global__ void __launch_bounds__(256, 3)
gather_gemm_kernel(const __half* __restrict__ xwh, const unsigned* __restrict__ csrw,
                   const unsigned* __restrict__ row_ptr,
                   const float* __restrict__ b1, const float* __restrict__ W2,
                   __half* __restrict__ Yh, int n) {
    __shared__ float4 Ws[64][16];  // Ws[k][j] = W2[k][4j..4j+3]
    for (int i = threadIdx.x; i < 64 * 16; i += blockDim.x)
        Ws[i >> 4][i & 15] = ((const float4*)W2)[i];
    __syncthreads();
    int lane = threadIdx.x & 63;
    int l8 = lane & 7;
    int gbase = lane & 56;
    int wid = blockIdx.x * (blockDim.x >> 6) + (threadIdx.x >> 6);
    int row = wid * 8 + (lane >> 3);
    if (row >= n) return;  // whole 8-lane group exits together (after Ws sync)
    unsigned start = row_ptr[row], end = row_ptr[row + 1];
    float di = rsqrtf((float)(end - start) + 1.0f);
    f8 acc = aggregate_row8(xwh, csrw, start, end, row, l8, gbase);
    float4 ba = ((const float4*)b1)[2 * l8];
    float4 bb = ((const float4*)b1)[2 * l8 + 1];
    float h0 = fmaxf(fmaf(di, acc.a.x, ba.x), 0.f);
    float h1 = fmaxf(fmaf(di, acc.a.y, ba.y), 0.f);
    float h2 = fmaxf(fmaf(di, acc.a.z, ba.z), 0.f);
    float h3 = fmaxf(fmaf(di, acc.a.w, ba.w), 0.f);
    float h4 = fmaxf(fmaf(di, acc.b.x, bb.x), 0.f);
    float h5 = fmaxf(fmaf(di, acc.b.y, bb.y), 0.f);
    float h6 = fmaxf(fmaf(di, acc.b.z, bb.z), 0.f);
    float h7 = fmaxf(fmaf(di, acc.b.w, bb.w), 0.f);
    // fused gemm: out[8*l8 + c] = sum_k h[k] * W2[k][8*l8+c]
    float4 o0 = make_float4(0.f, 0.f, 0.f, 0.f);
    float4 o1 = make_float4(0.f, 0.f, 0.f, 0.f);
#pragma unroll
    for (int k = 0; k < 64; ++k) {
        float comp = (k & 7) == 0 ? h0 : (k & 7) == 1 ? h1 : (k & 7) == 2 ? h2 :
                     (k & 7) == 3 ? h3 : (k & 7) == 4 ? h4 : (k & 7) == 5 ? h5 :
                     (k & 7) == 6 ? h6 : h7;
        float a = __shfl(comp, gbase + (k >> 3));
        float4 w0 = Ws[k][2 * l8];
        float4 w1 = Ws[k][2 * l8 + 1];
        o0.x = fmaf(a, w0.x, o0.x); o0.y = fmaf(a, w0.y, o0.y);
        o0.z = fmaf(a, w0.z, o0.z); o0.w = fmaf(a, w0.w, o0.w);
        o1.x = fmaf(a, w1.x, o1.x); o1.y = fmaf(a, w1.y, o1.y);
        o1.z = fmaf(a, w1.z, o1.z); o1.w = fmaf(a, w1.w, o1.w);
    }
    __half2 p0 = __floats2half2_rn(o0.x * di, o0.y * di);   // layer-2 prescale
    __half2 p1 = __floats2half2_rn(o0.z * di, o0.w * di);
    __half2 p2 = __floats2half2_rn(o1.x * di, o1.y * di);
    __half2 p3 = __floats2half2_rn(o1.z * di, o1.w * di);
    uint4 o;
    o.x = *(const unsigned*)&p0; o.y = *(const unsigned*)&p1;
    o.z = *(const unsigned*)&p2; o.w = *(const unsigned*)&p3;
    *(uint4*)(Yh + (size_t)row * 64 + 8 * l8) = o;   // 128 B contiguous: full lines
}

// ---- gather2: out = di*agg + b2 -> fp32 out (nontemporal: write-once) ----
__global__ void __launch_bounds__(256, 3)
gather_out_kernel(const __half* __restrict__ xwh, const unsigned* __restrict__ csrw,
                  const unsigned* __restrict__ row_ptr,
                  const float* __restrict__ bias, float4* __restrict__ out4, int n) {
    int lane = threadIdx.x & 63;
    int l8 = lane & 7;
    int gbase = lane & 56;
    int wid = blockIdx.x * (blockDim.x >> 6) + (threadIdx.x >> 6);
    int row = wid * 8 + (lane >> 3);
    if (row >= n) return;
    unsigned start = row_ptr[row], end = row_ptr[row + 1];
    float di = rsqrtf((float)(end - start) + 1.0f);
    f8 acc = aggregate_row8(xwh, csrw, start, end, row, l8, gbase);
    float4 ba = ((const float4*)bias)[2 * l8];
    float4 bb = ((const float4*)bias)[2 * l8 + 1];
    vfloat4 oa, ob;
    oa.x = fmaf(di, acc.a.x, ba.x); oa.y = fmaf(di, acc.a.y, ba.y);
    oa.z = fmaf(di, acc.a.z, ba.z); oa.w = fmaf(di, acc.a.w, ba.w);
    ob.x = fmaf(di, acc.b.x, bb.x); ob.y = fmaf(di, acc.b.y, bb.y);
    ob.z = fmaf(di, acc.b.z, bb.z); ob.w = fmaf(di, acc.b.w, bb.w);
    vfloat4* o4 = (vfloat4*)out4;
    __builtin_nontemporal_store(oa, &o4[(size_t)row * 16 + 2 * l8]);
    __builtin_nontemporal_store(ob, &o4[(size_t)row * 16 + 2 * l8 + 1]);
}

extern "C" void kernel_launch(void* const* d_in, const int* in_sizes, int n_in,
                              void* d_out, int out_size, void* d_ws, size_t ws_size,
                              hipStream_t stream) {
    const float* x  = (const float*)d_in[0];
    const int*   ei = (const int*)d_in[1];
    const float* W1 = (const float*)d_in[2];
    const float* b1 = (const float*)d_in[3];
    const float* W2 = (const float*)d_in[4];
    const float* b2 = (const float*)d_in[5];
    const int n = in_sizes[0] / 64;   // 50000 (packed paths require n <= 65535)
    const int e = in_sizes[1] / 2;    // 1600000
    const int* src = ei;              // edge_index[0]
    const int* dst = ei + e;          // edge_index[1]

    char* ws = (char*)d_ws;
    size_t off = 0;
    auto alloc = [&](size_t bytes) -> void* {
        void* p = ws + off;
        off = (off + bytes + 255) & ~(size_t)255;
        return p;
    };
    unsigned* rpf    = (unsigned*)alloc((size_t)(n + 1) * 4);
    unsigned* cursor = (unsigned*)alloc(256 * 4);                    // contiguous with deg:
    unsigned* deg    = (unsigned*)alloc((size_t)n * 4);              //   single memset below
    unsigned short* csr = (unsigned short*)alloc(((size_t)e / 2 + 64) * 4);  // 3.2 MB, word-padded
    const int B = (n + 255) / 256;                                   // 196 buckets
    unsigned* ebuf   = (unsigned*)alloc((size_t)B * BSTRIDE * 4);    // 12.85 MB (no overlay:
    __half*   xwh1   = (__half*)alloc((size_t)n * 64 * 2);           // concurrent with gemm)
    __half*   xwh2   = (__half*)alloc((size_t)n * 64 * 2);           // 6.4 MB
    float*    outf   = (float*)d_out;

    const int nbP1 = (e + P1_EDGES - 1) / P1_EDGES;   // 391 bucket blocks
    const int gblk64 = (n + 63) / 64;                 // 782 gemm blocks (64 rows each)

    // {bucket+deg || gemm-unscaled} -> statsfill(deg-scan + dinv-scale + fill) -> gathers
    hipMemsetAsync(cursor, 0, 256 * 4 + (size_t)n * 4, stream);   // cursor+deg contiguous
    bucket_gemm_kernel<<<nbP1 + gblk64, 1024, 0, stream>>>(
        src, dst, cursor, deg, ebuf, (const float4*)x, W1, xwh1, e, B, n, nbP1);
    statsfill_kernel<<<B, 1024, 0, stream>>>(ebuf, cursor, deg, rpf, xwh1, csr, n, e);

    const int gblk32 = (n + 31) / 32;   // gathers: 8 rows/wave

    // layer 1 (+fused layer-2 gemm), then layer 2 aggregate
    gather_gemm_kernel<<<gblk32, 256, 0, stream>>>(xwh1, (const unsigned*)csr, rpf, b1, W2, xwh2, n);
    gather_out_kernel<<<gblk32, 256, 0, stream>>>(xwh2, (const unsigned*)csr, rpf, b2, (float4*)outf, n);
}

// Round 10
// 203.003 us; speedup vs baseline: 1.0975x; 1.0975x over previous
//
#include <hip/hip_runtime.h>
#include <hip/hip_fp16.h>

// GCN 2-layer: out = A_hat @ relu(A_hat @ (X W1) + b1) W2 + b2
// A_hat = D^-1/2 (A+I) D^-1/2.
// R22 (post-mortem of R21's 222 us REGRESSION: 1.6M fire-and-forget global
// atomics on deg[] = 63.7 MB WRITE_SIZE in bucket, +70 us. RULE: any
// 1.6M-scale random device-scope atomic/store pass costs 50-100 us; only
// LDS-ranked bucketing is cheap. REVERTED to R20 statsfill/bucket.):
//   NEW: gather tables SPLIT into column-halves [n][32] fp16 (3.2 MB each,
//   < 4 MB per-XCD L2 -- the 6.4 MB table thrashed every XCD's L2, which
//   is why R18 occupancy + R19 dependency levers were null). Each gather
//   = 2 passes, 4-lane groups (16 rows/wave). Layer-1 pass A stores hA;
//   pass B aggregates half B, loads hA, runs the fused W2 gemm (lane owns
//   16 out cols), writes split xwh2A/B. Layer-2 = 2 independent passes.
// Kept: R20 mega-kernel (bucket || gemm1-unscaled split-write), statsfill
// (cursor self-scan + ebuf count/fill + in-place dinv scale of halves).

#define P1_EDGES 4096
#define BSTRIDE 16384   // ebuf slots per bucket (fixed stride), ~2x avg fill

typedef float vfloat4 __attribute__((ext_vector_type(4)));  // native vec for nt-store

// ---- mega kernel: blocks [0,nbP1) = edge bucketing; blocks [nbP1,...) =
// {xwA,xwB} = fp16(X @ W1) UNSCALED, split column-halves ----
__global__ void bucket_gemm_kernel(const int* __restrict__ src, const int* __restrict__ dst,
                                   unsigned* __restrict__ cursor, unsigned* __restrict__ ebuf,
                                   const float4* __restrict__ X4, const float* __restrict__ W,
                                   __half* __restrict__ YA, __half* __restrict__ YB,
                                   int e, int B, int n, int nbP1) {
    __shared__ unsigned hist[256];
    __shared__ unsigned base[256];
    __shared__ float4 Ws[64][16];
    int bid = blockIdx.x;
    if (bid < nbP1) {
        // ---- bucket branch: scatter edges by dst>>8; ebuf[slot]=dst<<16|src ----
        for (int i = threadIdx.x; i < B; i += 1024) hist[i] = 0;
        __syncthreads();
        int e0 = bid * P1_EDGES;
        int tbase = e0 + (int)threadIdx.x * 4;
        int4 sv = make_int4(0, 0, 0, 0), dv = make_int4(0, 0, 0, 0);
        if (tbase + 3 < e) {                       // vectorized 16B edge reads
            sv = ((const int4*)(src + e0))[threadIdx.x];
            dv = ((const int4*)(dst + e0))[threadIdx.x];
        } else {                                   // tail block only
            if (tbase + 0 < e) { sv.x = src[tbase + 0]; dv.x = dst[tbase + 0]; }
            if (tbase + 1 < e) { sv.y = src[tbase + 1]; dv.y = dst[tbase + 1]; }
            if (tbase + 2 < e) { sv.z = src[tbase + 2]; dv.z = dst[tbase + 2]; }
        }
        unsigned bk[4], rk[4], pk[4];
        bool vk[4];
#pragma unroll
        for (int k = 0; k < 4; ++k) {
            int t = tbase + k;
            vk[k] = (t < e);
            bk[k] = 0; rk[k] = 0; pk[k] = 0;
            if (vk[k]) {
                unsigned s = (unsigned)(k == 0 ? sv.x : k == 1 ? sv.y : k == 2 ? sv.z : sv.w);
                unsigned d = (unsigned)(k == 0 ? dv.x : k == 1 ? dv.y : k == 2 ? dv.z : dv.w);
                unsigned b = d >> 8;
                bk[k] = b;
                rk[k] = atomicAdd(&hist[b], 1u);     // rank within (block,bucket)
                pk[k] = (d << 16) | s;               // n < 2^16: both fit
            }
        }
        __syncthreads();
        for (int i = threadIdx.x; i < B; i += 1024)
            base[i] = hist[i] ? atomicAdd(&cursor[i], hist[i]) : 0u;
        __syncthreads();
#pragma unroll
        for (int k = 0; k < 4; ++k)
            if (vk[k]) {
                unsigned slot = base[bk[k]] + rk[k];
                if (slot < (unsigned)BSTRIDE)                  // overflow drop-guard
                    ebuf[(size_t)bk[k] * BSTRIDE + slot] = pk[k];
            }
    } else {
        // ---- gemm branch: {YA|YB}[row] = fp16(X[row] @ W), split halves ----
        for (int i = threadIdx.x; i < 64 * 16; i += 1024)
            Ws[i >> 4][i & 15] = ((const float4*)W)[i];
        __syncthreads();
        int lane = threadIdx.x & 63;
        int l = lane & 15;
        int gbase = lane & 48;
        int wid = (bid - nbP1) * 16 + (threadIdx.x >> 6);
        int row = wid * 4 + (lane >> 4);
        if (row >= n) return;
        float4 xv = X4[(size_t)row * 16 + l];
        float4 acc = make_float4(0.f, 0.f, 0.f, 0.f);
#pragma unroll
        for (int k = 0; k < 64; ++k) {
            float comp = (k & 3) == 0 ? xv.x : (k & 3) == 1 ? xv.y : (k & 3) == 2 ? xv.z : xv.w;
            float a = __shfl(comp, gbase + (k >> 2));
            float4 w = Ws[k][l];
            acc.x = fmaf(a, w.x, acc.x); acc.y = fmaf(a, w.y, acc.y);
            acc.z = fmaf(a, w.z, acc.z); acc.w = fmaf(a, w.w, acc.w);
        }
        __half2 h0 = __floats2half2_rn(acc.x, acc.y);
        __half2 h1 = __floats2half2_rn(acc.z, acc.w);
        uint2 o;
        o.x = *(const unsigned*)&h0;
        o.y = *(const unsigned*)&h1;
        __half* dstp = (l < 8 ? YA : YB) + ((size_t)row << 5) + 4 * (l & 7);
        *(uint2*)dstp = o;
    }
}

// ---- statsfill (R20 form + split scale): cursor self-scan -> ebuf count
// -> local scan -> rpf -> scale xwA/xwB window rows by dinv -> ebuf fill
// -> csr[slot] = src (ushort) ----
__global__ void statsfill_kernel(const unsigned* __restrict__ ebuf,
                                 const unsigned* __restrict__ bcnt,
                                 unsigned* __restrict__ rpf,
                                 __half* __restrict__ xwA, __half* __restrict__ xwB,
                                 unsigned short* __restrict__ csr, int n, int e) {
    __shared__ unsigned pos[256];
    __shared__ unsigned sh[256];
    __shared__ unsigned rpl[256];
    __shared__ float dl[256];
    __shared__ unsigned bs;        // bstart[b] = sum of bcnt[0..b)
    int b = blockIdx.x;
    int w0 = b << 8;
    int wlen = min(w0 + 256, n) - w0;
    unsigned c0 = 0;
    if (threadIdx.x < 256) { c0 = bcnt[threadIdx.x]; sh[threadIdx.x] = c0; }
    __syncthreads();
    for (int off = 1; off < 256; off <<= 1) {
        unsigned t = 0;
        if (threadIdx.x < 256 && threadIdx.x >= (unsigned)off) t = sh[threadIdx.x - off];
        __syncthreads();
        if (threadIdx.x < 256) sh[threadIdx.x] += t;
        __syncthreads();
    }
    if (threadIdx.x == (unsigned)b) bs = sh[b] - c0;   // exclusive prefix at b
    if (threadIdx.x < 256) pos[threadIdx.x] = 0;
    __syncthreads();
    unsigned cnt = bcnt[b];
    const unsigned* eb = ebuf + (size_t)b * BSTRIDE;
    for (unsigned j = threadIdx.x; j < cnt; j += 1024)
        atomicAdd(&pos[(eb[j] >> 16) - w0], 1u);
    __syncthreads();
    unsigned v = 0;
    if (threadIdx.x < 256) { v = pos[threadIdx.x]; sh[threadIdx.x] = v; }
    __syncthreads();
    for (int off = 1; off < 256; off <<= 1) {
        unsigned t = 0;
        if (threadIdx.x < 256 && threadIdx.x >= (unsigned)off) t = sh[threadIdx.x - off];
        __syncthreads();
        if (threadIdx.x < 256) sh[threadIdx.x] += t;
        __syncthreads();
    }
    if (threadIdx.x < 256) {
        unsigned rp = bs + sh[threadIdx.x] - v;          // global base + excl scan
        rpl[threadIdx.x] = rp;
        dl[threadIdx.x] = rsqrtf((float)v + 1.0f);       // +1 self-loop
        if ((int)threadIdx.x < wlen) rpf[w0 + threadIdx.x] = rp;
        pos[threadIdx.x] = 0;                            // reset for fill phase
    }
    if (b == (int)gridDim.x - 1 && threadIdx.x == 0) rpf[n] = (unsigned)e;
    __syncthreads();
    // phase S: scale window rows of BOTH halves by dinv, in place.
    // 8 uint4 chunks per row (4 in A, 4 in B).
    for (int i = threadIdx.x; i < (wlen << 3); i += 1024) {
        int r = i >> 3, c = i & 7;
        float di = dl[r];
        __half* tb = (c < 4) ? xwA : xwB;
        uint4* p16 = (uint4*)(tb + ((size_t)(w0 + r) << 5)) + (c & 3);
        uint4 hv = *p16;
        float2 f0 = __half22float2(*(const __half2*)&hv.x);
        float2 f1 = __half22float2(*(const __half2*)&hv.y);
        float2 f2 = __half22float2(*(const __half2*)&hv.z);
        float2 f3 = __half22float2(*(const __half2*)&hv.w);
        __half2 g0 = __floats2half2_rn(f0.x * di, f0.y * di);
        __half2 g1 = __floats2half2_rn(f1.x * di, f1.y * di);
        __half2 g2 = __floats2half2_rn(f2.x * di, f2.y * di);
        __half2 g3 = __floats2half2_rn(f3.x * di, f3.y * di);
        hv.x = *(const unsigned*)&g0; hv.y = *(const unsigned*)&g1;
        hv.z = *(const unsigned*)&g2; hv.w = *(const unsigned*)&g3;
        *p16 = hv;
    }
    // phase F: fill csr (LDS pos ranking)
    for (unsigned j = threadIdx.x; j < cnt; j += 1024) {
        unsigned p = eb[j];                              // L2-hot
        unsigned d = (p >> 16) - w0;
        unsigned r = atomicAdd(&pos[d], 1u);
        csr[rpl[d] + r] = (unsigned short)(p & 0xffffu);
    }
}

// ---- half-table aggregation: 4-lane group per dst row; lane l4 owns cols
// 8*l4..8*l4+7 of the 32-col half. csr words via lane l4 + shfl (4 words =
// 8 edges per step); head/tail via 0/1 weights. Rows prescaled. ----
struct f8 { float4 a, b; };

__device__ __forceinline__ f8 aggregate_half(const __half* __restrict__ xw,
                                             const unsigned* __restrict__ csrw,
                                             unsigned start, unsigned end,
                                             int row, int l4, int gb) {
    f8 acc;
    {   // self-loop term
        uint4 hv = *(const uint4*)(xw + ((size_t)row << 5) + 8 * l4);
        float2 f0 = __half22float2(*(const __half2*)&hv.x);
        float2 f1 = __half22float2(*(const __half2*)&hv.y);
        float2 f2 = __half22float2(*(const __half2*)&hv.z);
        float2 f3 = __half22float2(*(const __half2*)&hv.w);
        acc.a = make_float4(f0.x, f0.y, f1.x, f1.y);
        acc.b = make_float4(f2.x, f2.y, f3.x, f3.y);
    }
    unsigned wb = start >> 1;
    unsigned jw = wb + (unsigned)l4;
    unsigned ed = (jw * 2 < end) ? __builtin_nontemporal_load(&csrw[jw]) : 0u;
    for (unsigned base = wb; base * 2 < end; base += 4) {
        unsigned jn = base + 4 + (unsigned)l4;
        unsigned ed_next = (jn * 2 < end) ? __builtin_nontemporal_load(&csrw[jn]) : 0u;
#pragma unroll
        for (int t = 0; t < 4; ++t) {
            unsigned p = __shfl(ed, gb + t);
            unsigned i0 = (base + (unsigned)t) * 2;
            int s0 = (int)(p & 0xffffu);
            int s1 = (int)(p >> 16);
            float w0 = (i0 >= start && i0 < end) ? 1.0f : 0.0f;
            float w1 = (i0 + 1 < end) ? 1.0f : 0.0f;
            uint4 hv0 = *(const uint4*)(xw + ((size_t)s0 << 5) + 8 * l4);
            uint4 hv1 = *(const uint4*)(xw + ((size_t)s1 << 5) + 8 * l4);
            float2 a0 = __half22float2(*(const __half2*)&hv0.x);
            float2 a1 = __half22float2(*(const __half2*)&hv0.y);
            float2 a2 = __half22float2(*(const __half2*)&hv0.z);
            float2 a3 = __half22float2(*(const __half2*)&hv0.w);
            acc.a.x = fmaf(w0, a0.x, acc.a.x); acc.a.y = fmaf(w0, a0.y, acc.a.y);
            acc.a.z = fmaf(w0, a1.x, acc.a.z); acc.a.w = fmaf(w0, a1.y, acc.a.w);
            acc.b.x = fmaf(w0, a2.x, acc.b.x); acc.b.y = fmaf(w0, a2.y, acc.b.y);
            acc.b.z = fmaf(w0, a3.x, acc.b.z); acc.b.w = fmaf(w0, a3.y, acc.b.w);
            float2 c0 = __half22float2(*(const __half2*)&hv1.x);
            float2 c1 = __half22float2(*(const __half2*)&hv1.y);
            float2 c2 = __half22float2(*(const __half2*)&hv1.z);
            float2 c3 = __half22float2(*(const __half2*)&hv1.w);
            acc.a.x = fmaf(w1, c0.x, acc.a.x); acc.a.y = fmaf(w1, c0.y, acc.a.y);
            acc.a.z = fmaf(w1, c1.x, acc.a.z); acc.a.w = fmaf(w1, c1.y, acc.a.w);
            acc.b.x = fmaf(w1, c2.x, acc.b.x); acc.b.y = fmaf(w1, c2.y, acc.b.y);
            acc.b.z = fmaf(w1, c3.x, acc.b.z); acc.b.w = fmaf(w1, c3.y, acc.b.w);
        }
        ed = ed_next;
    }
    return acc;
}

// ---- gather1 pass A: hA = fp16(relu(di*aggA + b1[0:32])) ----
__global__ void __launch_bounds__(256, 3)
gather1A_kernel(const __half* __restrict__ xwA, const unsigned* __restrict__ csrw,
                const unsigned* __restrict__ row_ptr, const float* __restrict__ b1,
                __half* __restrict__ hA, int n) {
    int lane = threadIdx.x & 63;
    int l4 = lane & 3;
    int gb = lane & 60;
    int wid = blockIdx.x * (blockDim.x >> 6) + (threadIdx.x >> 6);
    int row = wid * 16 + (lane >> 2);
    if (row >= n) return;
    unsigned start = row_ptr[row], end = row_ptr[row + 1];
    float di = rsqrtf((float)(end - start) + 1.0f);
    f8 acc = aggregate_half(xwA, csrw, start, end, row, l4, gb);
    float4 ba = ((const float4*)b1)[2 * l4];
    float4 bb = ((const float4*)b1)[2 * l4 + 1];
    __half2 p0 = __floats2half2_rn(fmaxf(fmaf(di, acc.a.x, ba.x), 0.f), fmaxf(fmaf(di, acc.a.y, ba.y), 0.f));
    __half2 p1 = __floats2half2_rn(fmaxf(fmaf(di, acc.a.z, ba.z), 0.f), fmaxf(fmaf(di, acc.a.w, ba.w), 0.f));
    __half2 p2 = __floats2half2_rn(fmaxf(fmaf(di, acc.b.x, bb.x), 0.f), fmaxf(fmaf(di, acc.b.y, bb.y), 0.f));
    __half2 p3 = __floats2half2_rn(fmaxf(fmaf(di, acc.b.z, bb.z), 0.f), fmaxf(fmaf(di, acc.b.w, bb.w), 0.f));
    uint4 o;
    o.x = *(const unsigned*)&p0; o.y = *(const unsigned*)&p1;
    o.z = *(const unsigned*)&p2; o.w = *(const unsigned*)&p3;
    *(uint4*)(hA + ((size_t)row << 5) + 8 * l4) = o;
}

// ---- gather1 pass B + fused gemm2: hB in regs, hA loaded; full-h shfl
// gemm vs LDS W2; lane owns 16 out cols; writes split xw2A/xw2B ----
__global__ void __launch_bounds__(256, 3)
gather1B_kernel(const __half* __restrict__ xwB, const unsigned* __restrict__ csrw,
                const unsigned* __restrict__ row_ptr, const float* __restrict__ b1,
                const __half* __restrict__ hA, const float* __restrict__ W2,
                __half* __restrict__ xw2A, __half* __restrict__ xw2B, int n) {
    __shared__ float4 Ws[64][16];  // Ws[k][j] = W2[k][4j..4j+3]
    for (int i = threadIdx.x; i < 64 * 16; i += blockDim.x)
        Ws[i >> 4][i & 15] = ((const float4*)W2)[i];
    __syncthreads();
    int lane = threadIdx.x & 63;
    int l4 = lane & 3;
    int gb = lane & 60;
    int wid = blockIdx.x * (blockDim.x >> 6) + (threadIdx.x >> 6);
    int row = wid * 16 + (lane >> 2);
    if (row >= n) return;   // 4-lane group exits together (after Ws sync)
    unsigned start = row_ptr[row], end = row_ptr[row + 1];
    float di = rsqrtf((float)(end - start) + 1.0f);
    f8 acc = aggregate_half(xwB, csrw, start, end, row, l4, gb);
    float4 ba = ((const float4*)b1)[8 + 2 * l4];        // cols 32+8*l4
    float4 bb = ((const float4*)b1)[8 + 2 * l4 + 1];
    float hb0 = fmaxf(fmaf(di, acc.a.x, ba.x), 0.f);
    float hb1 = fmaxf(fmaf(di, acc.a.y, ba.y), 0.f);
    float hb2 = fmaxf(fmaf(di, acc.a.z, ba.z), 0.f);
    float hb3 = fmaxf(fmaf(di, acc.a.w, ba.w), 0.f);
    float hb4 = fmaxf(fmaf(di, acc.b.x, bb.x), 0.f);
    float hb5 = fmaxf(fmaf(di, acc.b.y, bb.y), 0.f);
    float hb6 = fmaxf(fmaf(di, acc.b.z, bb.z), 0.f);
    float hb7 = fmaxf(fmaf(di, acc.b.w, bb.w), 0.f);
    uint4 hv = *(const uint4*)(hA + ((size_t)row << 5) + 8 * l4);
    float2 q0 = __half22float2(*(const __half2*)&hv.x);
    float2 q1 = __half22float2(*(const __half2*)&hv.y);
    float2 q2 = __half22float2(*(const __half2*)&hv.z);
    float2 q3 = __half22float2(*(const __half2*)&hv.w);
    float ha0 = q0.x, ha1 = q0.y, ha2 = q1.x, ha3 = q1.y;
    float ha4 = q2.x, ha5 = q2.y, ha6 = q3.x, ha7 = q3.y;
    // gemm: lane owns out cols 16*l4 .. 16*l4+15
    float4 o0 = make_float4(0.f, 0.f, 0.f, 0.f);
    float4 o1 = make_float4(0.f, 0.f, 0.f, 0.f);
    float4 o2 = make_float4(0.f, 0.f, 0.f, 0.f);
    float4 o3 = make_float4(0.f, 0.f, 0.f, 0.f);
#pragma unroll
    for (int k = 0; k < 64; ++k) {
        float va = (k & 7) == 0 ? ha0 : (k & 7) == 1 ? ha1 : (k & 7) == 2 ? ha2 :
                   (k & 7) == 3 ? ha3 : (k & 7) == 4 ? ha4 : (k & 7) == 5 ? ha5 :
                   (k & 7) == 6 ? ha6 : ha7;
        float vb = (k & 7) == 0 ? hb0 : (k & 7) == 1 ? hb1 : (k & 7) == 2 ? hb2 :
                   (k & 7) == 3 ? hb3 : (k & 7) == 4 ? hb4 : (k & 7) == 5 ? hb5 :
                   (k & 7) == 6 ? hb6 : hb7;
        float comp = (k < 32) ? va : vb;                 // folds at compile time
        float a = __shfl(comp, gb + ((k >> 3) & 3));
        float4 w0 = Ws[k][4 * l4 + 0];
        float4 w1 = Ws[k][4 * l4 + 1];
        float4 w2 = Ws[k][4 * l4 + 2];
        float4 w3 = Ws[k][4 * l4 + 3];
        o0.x = fmaf(a, w0.x, o0.x); o0.y = fmaf(a, w0.y, o0.y);
        o0.z = fmaf(a, w0.z, o0.z); o0.w = fmaf(a, w0.w, o0.w);
        o1.x = fmaf(a, w1.x, o1.x); o1.y = fmaf(a, w1.y, o1.y);
        o1.z = fmaf(a, w1.z, o1.z); o1.w = fmaf(a, w1.w, o1.w);
        o2.x = fmaf(a, w2.x, o2.x); o2.y = fmaf(a, w2.y, o2.y);
        o2.z = fmaf(a, w2.z, o2.z); o2.w = fmaf(a, w2.w, o2.w);
        o3.x = fmaf(a, w3.x, o3.x); o3.y = fmaf(a, w3.y, o3.y);
        o3.z = fmaf(a, w3.z, o3.z); o3.w = fmaf(a, w3.w, o3.w);
    }
    __half2 p0 = __floats2half2_rn(o0.x * di, o0.y * di);   // layer-2 prescale
    __half2 p1 = __floats2half2_rn(o0.z * di, o0.w * di);
    __half2 p2 = __floats2half2_rn(o1.x * di, o1.y * di);
    __half2 p3 = __floats2half2_rn(o1.z * di, o1.w * di);
    __half2 p4 = __floats2half2_rn(o2.x * di, o2.y * di);
    __half2 p5 = __floats2half2_rn(o2.z * di, o2.w * di);
    __half2 p6 = __floats2half2_rn(o3.x * di, o3.y * di);
    __half2 p7 = __floats2half2_rn(o3.z * di, o3.w * di);
    uint4 u0, u1;
    u0.x = *(const unsigned*)&p0; u0.y = *(const unsigned*)&p1;
    u0.z = *(const unsigned*)&p2; u0.w = *(const unsigned*)&p3;
    u1.x = *(const unsigned*)&p4; u1.y = *(const unsigned*)&p5;
    u1.z = *(const unsigned*)&p6; u1.w = *(const unsigned*)&p7;
    __half* dstp = (l4 < 2 ? xw2A : xw2B) + ((size_t)row << 5) + 16 * (l4 & 1);
    *(uint4*)dstp = u0;
    *(uint4*)(dstp + 8) = u1;
}

// ---- gather2 half-pass: out[:, colOff:colOff+32] = di*agg(xw2H) + b2 ----
__global__ void __launch_bounds__(256, 3)
gather2_kernel(const __half* __restrict__ xw2H, const unsigned* __restrict__ csrw,
               const unsigned* __restrict__ row_ptr, const float* __restrict__ b2,
               float* __restrict__ outp, int colOff, int n) {
    int lane = threadIdx.x & 63;
    int l4 = lane & 3;
    int gb = lane & 60;
    int wid = blockIdx.x * (blockDim.x >> 6) + (threadIdx.x >> 6);
    int row = wid * 16 + (lane >> 2);
    if (row >= n) return;
    unsigned start = row_ptr[row], end = row_ptr[row + 1];
    float di = rsqrtf((float)(end - start) + 1.0f);
    f8 acc = aggregate_half(xw2H, csrw, start, end, row, l4, gb);
    float4 ba = ((const float4*)b2)[(colOff >> 2) + 2 * l4];
    float4 bb = ((const float4*)b2)[(colOff >> 2) + 2 * l4 + 1];
    vfloat4 oa, ob;
    oa.x = fmaf(di, acc.a.x, ba.x); oa.y = fmaf(di, acc.a.y, ba.y);
    oa.z = fmaf(di, acc.a.z, ba.z); oa.w = fmaf(di, acc.a.w, ba.w);
    ob.x = fmaf(di, acc.b.x, bb.x); ob.y = fmaf(di, acc.b.y, bb.y);
    ob.z = fmaf(di, acc.b.z, bb.z); ob.w = fmaf(di, acc.b.w, bb.w);
    vfloat4* o4 = (vfloat4*)(outp + (size_t)row * 64 + colOff + 8 * l4);
    __builtin_nontemporal_store(oa, o4);
    __builtin_nontemporal_store(ob, o4 + 1);
}

extern "C" void kernel_launch(void* const* d_in, const int* in_sizes, int n_in,
                              void* d_out, int out_size, void* d_ws, size_t ws_size,
                              hipStream_t stream) {
    const float* x  = (const float*)d_in[0];
    const int*   ei = (const int*)d_in[1];
    const float* W1 = (const float*)d_in[2];
    const float* b1 = (const float*)d_in[3];
    const float* W2 = (const float*)d_in[4];
    const float* b2 = (const float*)d_in[5];
    const int n = in_sizes[0] / 64;   // 50000 (packed paths require n <= 65535)
    const int e = in_sizes[1] / 2;    // 1600000
    const int* src = ei;              // edge_index[0]
    const int* dst = ei + e;          // edge_index[1]

    char* ws = (char*)d_ws;
    size_t off = 0;
    auto alloc = [&](size_t bytes) -> void* {
        void* p = ws + off;
        off = (off + bytes + 255) & ~(size_t)255;
        return p;
    };
    unsigned* rpf    = (unsigned*)alloc((size_t)(n + 1) * 4);
    unsigned* cursor = (unsigned*)alloc(256 * 4);
    unsigned short* csr = (unsigned short*)alloc(((size_t)e / 2 + 64) * 4);  // 3.2 MB, word-padded
    const int B = (n + 255) / 256;                                   // 196 buckets
    unsigned* ebuf  = (unsigned*)alloc((size_t)B * BSTRIDE * 4);     // 12.85 MB
    size_t half = (size_t)n * 32 * 2;                                // 3.2 MB per half-table
    __half* xw1A = (__half*)alloc(half);
    __half* xw1B = (__half*)alloc(half);
    __half* hA   = (__half*)alloc(half);
    __half* xw2A = (__half*)alloc(half);
    __half* xw2B = (__half*)alloc(half);
    float*  outf = (float*)d_out;

    const int nbP1 = (e + P1_EDGES - 1) / P1_EDGES;   // 391 bucket blocks
    const int gblk64 = (n + 63) / 64;                 // 782 gemm blocks (64 rows each)

    // {bucket || gemm1-split-unscaled} -> statsfill(+dinv-scale of halves)
    hipMemsetAsync(cursor, 0, 256 * 4, stream);
    bucket_gemm_kernel<<<nbP1 + gblk64, 1024, 0, stream>>>(
        src, dst, cursor, ebuf, (const float4*)x, W1, xw1A, xw1B, e, B, n, nbP1);
    statsfill_kernel<<<B, 1024, 0, stream>>>(ebuf, cursor, rpf, xw1A, xw1B, csr, n, e);

    const int gblk = (n + 63) / 64;   // gathers: 16 rows/wave, 4 waves/block

    // layer 1: pass A -> hA; pass B (+fused W2 gemm) -> split xw2A/xw2B
    gather1A_kernel<<<gblk, 256, 0, stream>>>(xw1A, (const unsigned*)csr, rpf, b1, hA, n);
    gather1B_kernel<<<gblk, 256, 0, stream>>>(xw1B, (const unsigned*)csr, rpf, b1, hA, W2, xw2A, xw2B, n);

    // layer 2: two independent half-passes
    gather2_kernel<<<gblk, 256, 0, stream>>>(xw2A, (const unsigned*)csr, rpf, b2, outf, 0, n);
    gather2_kernel<<<gblk, 256, 0, stream>>>(xw2B, (const unsigned*)csr, rpf, b2, outf, 32, n);
}

// Round 11
// 172.209 us; speedup vs baseline: 1.2937x; 1.1788x over previous
//
#include <hip/hip_runtime.h>
#include <hip/hip_fp16.h>

// GCN 2-layer: out = A_hat @ relu(A_hat @ (X W1) + b1) W2 + b2
// A_hat = D^-1/2 (A+I) D^-1/2.
// R23 = REVERT to R20 (measured best, 170.8 us). R22's split-table
// experiment regressed (+32 us: halving the per-edge payload doubled the
// per-edge walk -- csr re-read + shfl/guard overhead x2). Full branch
// history now measured:
//   - CSR build: direct atomic fill (+110), fence-fused scan (+220),
//     global-atomic deg (+70) -- bucketed LDS-ranked build is optimal.
//   - Gathers: occupancy null, shfl-chain null, table-split negative.
//     Floor: 2 x 205 MB random 128 B rows @ ~5 TB/s L2/L3 ~= 80 us.
//   - bucket || gemm1 overlap: confirmed -5 us (kept).
// Structure: {bucket || gemm1-unscaled} -> statsfill (cursor self-scan,
// fence-free; ebuf count+fill; in-place dinv scale of xwh1) ->
// gather_gemm (agg + relu + fused W2 gemm) -> gather_out.

#define P1_EDGES 4096
#define BSTRIDE 16384   // ebuf slots per bucket (fixed stride), ~2x avg fill

typedef float vfloat4 __attribute__((ext_vector_type(4)));  // native vec for nt-store

// ---- mega kernel: blocks [0,nbP1) = edge bucketing; blocks [nbP1, ...) =
// xw1 = fp16(X @ W1) UNSCALED (16 waves, 4 rows/wave, 64 rows/block) ----
__global__ void bucket_gemm_kernel(const int* __restrict__ src, const int* __restrict__ dst,
                                   unsigned* __restrict__ cursor, unsigned* __restrict__ ebuf,
                                   const float4* __restrict__ X4, const float* __restrict__ W,
                                   __half* __restrict__ Yh,
                                   int e, int B, int n, int nbP1) {
    __shared__ unsigned hist[256];
    __shared__ unsigned base[256];
    __shared__ float4 Ws[64][16];
    int bid = blockIdx.x;
    if (bid < nbP1) {
        // ---- bucket branch: scatter edges by dst>>8; ebuf[slot]=dst<<16|src ----
        for (int i = threadIdx.x; i < B; i += 1024) hist[i] = 0;
        __syncthreads();
        int e0 = bid * P1_EDGES;
        int tbase = e0 + (int)threadIdx.x * 4;
        int4 sv = make_int4(0, 0, 0, 0), dv = make_int4(0, 0, 0, 0);
        if (tbase + 3 < e) {                       // vectorized 16B edge reads
            sv = ((const int4*)(src + e0))[threadIdx.x];
            dv = ((const int4*)(dst + e0))[threadIdx.x];
        } else {                                   // tail block only
            if (tbase + 0 < e) { sv.x = src[tbase + 0]; dv.x = dst[tbase + 0]; }
            if (tbase + 1 < e) { sv.y = src[tbase + 1]; dv.y = dst[tbase + 1]; }
            if (tbase + 2 < e) { sv.z = src[tbase + 2]; dv.z = dst[tbase + 2]; }
        }
        unsigned bk[4], rk[4], pk[4];
        bool vk[4];
#pragma unroll
        for (int k = 0; k < 4; ++k) {
            int t = tbase + k;
            vk[k] = (t < e);
            bk[k] = 0; rk[k] = 0; pk[k] = 0;
            if (vk[k]) {
                unsigned s = (unsigned)(k == 0 ? sv.x : k == 1 ? sv.y : k == 2 ? sv.z : sv.w);
                unsigned d = (unsigned)(k == 0 ? dv.x : k == 1 ? dv.y : k == 2 ? dv.z : dv.w);
                unsigned b = d >> 8;
                bk[k] = b;
                rk[k] = atomicAdd(&hist[b], 1u);     // rank within (block,bucket)
                pk[k] = (d << 16) | s;               // n < 2^16: both fit
            }
        }
        __syncthreads();
        for (int i = threadIdx.x; i < B; i += 1024)
            base[i] = hist[i] ? atomicAdd(&cursor[i], hist[i]) : 0u;
        __syncthreads();
#pragma unroll
        for (int k = 0; k < 4; ++k)
            if (vk[k]) {
                unsigned slot = base[bk[k]] + rk[k];
                if (slot < (unsigned)BSTRIDE)                  // overflow drop-guard
                    ebuf[(size_t)bk[k] * BSTRIDE + slot] = pk[k];
            }
    } else {
        // ---- gemm branch: Yh[row] = fp16(X[row] @ W) (no prescale) ----
        for (int i = threadIdx.x; i < 64 * 16; i += 1024)
            Ws[i >> 4][i & 15] = ((const float4*)W)[i];
        __syncthreads();
        int lane = threadIdx.x & 63;
        int l = lane & 15;
        int gbase = lane & 48;
        int wid = (bid - nbP1) * 16 + (threadIdx.x >> 6);
        int row = wid * 4 + (lane >> 4);
        if (row >= n) return;
        float4 xv = X4[(size_t)row * 16 + l];
        float4 acc = make_float4(0.f, 0.f, 0.f, 0.f);
#pragma unroll
        for (int k = 0; k < 64; ++k) {
            float comp = (k & 3) == 0 ? xv.x : (k & 3) == 1 ? xv.y : (k & 3) == 2 ? xv.z : xv.w;
            float a = __shfl(comp, gbase + (k >> 2));
            float4 w = Ws[k][l];
            acc.x = fmaf(a, w.x, acc.x); acc.y = fmaf(a, w.y, acc.y);
            acc.z = fmaf(a, w.z, acc.z); acc.w = fmaf(a, w.w, acc.w);
        }
        __half2 h0 = __floats2half2_rn(acc.x, acc.y);
        __half2 h1 = __floats2half2_rn(acc.z, acc.w);
        uint2 o;
        o.x = *(const unsigned*)&h0;
        o.y = *(const unsigned*)&h1;
        *(uint2*)(Yh + (size_t)row * 64 + 4 * l) = o;
    }
}

// ---- fused per-bucket stats + fill + xwh1 scale. Phase 0: in-block scan
// of cursor -> bstart (fence-free: kernel boundary orders it).
// Then: count -> local scan -> rpf -> scale xwh1 window rows by dinv (in
// place) -> re-read ebuf (L2-hot) -> csr[slot] = src (ushort) ----
__global__ void statsfill_kernel(const unsigned* __restrict__ ebuf,
                                 const unsigned* __restrict__ bcnt,
                                 unsigned* __restrict__ rpf,
                                 __half* __restrict__ xwh1,
                                 unsigned short* __restrict__ csr, int n, int e) {
    __shared__ unsigned pos[256];
    __shared__ unsigned sh[256];
    __shared__ unsigned rpl[256];
    __shared__ float dl[256];
    __shared__ unsigned bs;        // bstart[b] = sum of bcnt[0..b)
    int b = blockIdx.x;
    int w0 = b << 8;
    int wlen = min(w0 + 256, n) - w0;
    // phase 0: global bucket-prefix for this block
    unsigned c0 = 0;
    if (threadIdx.x < 256) { c0 = bcnt[threadIdx.x]; sh[threadIdx.x] = c0; }
    __syncthreads();
    for (int off = 1; off < 256; off <<= 1) {
        unsigned t = 0;
        if (threadIdx.x < 256 && threadIdx.x >= (unsigned)off) t = sh[threadIdx.x - off];
        __syncthreads();
        if (threadIdx.x < 256) sh[threadIdx.x] += t;
        __syncthreads();
    }
    if (threadIdx.x == (unsigned)b) bs = sh[b] - c0;   // exclusive prefix at b
    if (threadIdx.x < 256) pos[threadIdx.x] = 0;
    __syncthreads();
    unsigned cnt = bcnt[b];
    const unsigned* eb = ebuf + (size_t)b * BSTRIDE;
    for (unsigned j = threadIdx.x; j < cnt; j += 1024)
        atomicAdd(&pos[(eb[j] >> 16) - w0], 1u);
    __syncthreads();
    unsigned v = 0;
    if (threadIdx.x < 256) { v = pos[threadIdx.x]; sh[threadIdx.x] = v; }
    __syncthreads();
    for (int off = 1; off < 256; off <<= 1) {
        unsigned t = 0;
        if (threadIdx.x < 256 && threadIdx.x >= (unsigned)off) t = sh[threadIdx.x - off];
        __syncthreads();
        if (threadIdx.x < 256) sh[threadIdx.x] += t;
        __syncthreads();
    }
    if (threadIdx.x < 256) {
        unsigned rp = bs + sh[threadIdx.x] - v;          // global base + excl scan
        rpl[threadIdx.x] = rp;
        dl[threadIdx.x] = rsqrtf((float)v + 1.0f);       // +1 self-loop
        if ((int)threadIdx.x < wlen) rpf[w0 + threadIdx.x] = rp;
        pos[threadIdx.x] = 0;                            // reset for fill phase
    }
    if (b == (int)gridDim.x - 1 && threadIdx.x == 0) rpf[n] = (unsigned)e;
    __syncthreads();
    // phase S: scale xwh1 rows [w0, w0+wlen) by dinv, in place.
    for (int i = threadIdx.x; i < (wlen << 3); i += 1024) {
        int r = i >> 3, c = i & 7;
        float di = dl[r];
        uint4* p16 = (uint4*)(xwh1 + ((size_t)(w0 + r) << 6)) + c;
        uint4 hv = *p16;
        float2 f0 = __half22float2(*(const __half2*)&hv.x);
        float2 f1 = __half22float2(*(const __half2*)&hv.y);
        float2 f2 = __half22float2(*(const __half2*)&hv.z);
        float2 f3 = __half22float2(*(const __half2*)&hv.w);
        __half2 g0 = __floats2half2_rn(f0.x * di, f0.y * di);
        __half2 g1 = __floats2half2_rn(f1.x * di, f1.y * di);
        __half2 g2 = __floats2half2_rn(f2.x * di, f2.y * di);
        __half2 g3 = __floats2half2_rn(f3.x * di, f3.y * di);
        hv.x = *(const unsigned*)&g0; hv.y = *(const unsigned*)&g1;
        hv.z = *(const unsigned*)&g2; hv.w = *(const unsigned*)&g3;
        *p16 = hv;
    }
    // phase F: fill csr (single ebuf pass, LDS pos ranking)
    for (unsigned j = threadIdx.x; j < cnt; j += 1024) {
        unsigned p = eb[j];                              // L2-hot
        unsigned d = (p >> 16) - w0;
        unsigned r = atomicAdd(&pos[d], 1u);
        csr[rpl[d] + r] = (unsigned short)(p & 0xffffu);
    }
}

// ---- aggregation core (R18 form): 8-lane group per dst row; lane l8 owns
// cols 8*l8..8*l8+7. csr ushort read as uint words (2 edges/word) via lane
// l8 + shfl broadcast; head/tail via 0/1 weights. Rows prescaled. ----
struct f8 { float4 a, b; };

__device__ __forceinline__ f8 aggregate_row8(const __half* __restrict__ xwh,
                                             const unsigned* __restrict__ csrw,
                                             unsigned start, unsigned end,
                                             int row, int l8, int gbase) {
    f8 acc;
    {   // self-loop term: xwh'[row] (prescaled) with weight 1
        uint4 hv = *(const uint4*)(xwh + (size_t)row * 64 + 8 * l8);
        float2 f0 = __half22float2(*(const __half2*)&hv.x);
        float2 f1 = __half22float2(*(const __half2*)&hv.y);
        float2 f2 = __half22float2(*(const __half2*)&hv.z);
        float2 f3 = __half22float2(*(const __half2*)&hv.w);
        acc.a = make_float4(f0.x, f0.y, f1.x, f1.y);
        acc.b = make_float4(f2.x, f2.y, f3.x, f3.y);
    }
    unsigned wb = start >> 1;                        // first csr word
    unsigned jw = wb + (unsigned)l8;
    unsigned ed = (jw * 2 < end) ? __builtin_nontemporal_load(&csrw[jw]) : 0u;
    for (unsigned base = wb; base * 2 < end; base += 8) {
        unsigned jn = base + 8 + (unsigned)l8;
        unsigned ed_next = (jn * 2 < end) ? __builtin_nontemporal_load(&csrw[jn]) : 0u;
#pragma unroll
        for (int t = 0; t < 8; ++t) {
            unsigned p = __shfl(ed, gbase + t);
            unsigned i0 = (base + (unsigned)t) * 2;          // edge idx of lo half
            int s0 = (int)(p & 0xffffu);
            int s1 = (int)(p >> 16);
            float w0 = (i0 >= start && i0 < end) ? 1.0f : 0.0f;  // head+tail guard
            float w1 = (i0 + 1 < end) ? 1.0f : 0.0f;             // i0+1 >= start always
            uint4 hv0 = *(const uint4*)(xwh + (size_t)s0 * 64 + 8 * l8);
            uint4 hv1 = *(const uint4*)(xwh + (size_t)s1 * 64 + 8 * l8);
            float2 a0 = __half22float2(*(const __half2*)&hv0.x);
            float2 a1 = __half22float2(*(const __half2*)&hv0.y);
            float2 a2 = __half22float2(*(const __half2*)&hv0.z);
            float2 a3 = __half22float2(*(const __half2*)&hv0.w);
            acc.a.x = fmaf(w0, a0.x, acc.a.x); acc.a.y = fmaf(w0, a0.y, acc.a.y);
            acc.a.z = fmaf(w0, a1.x, acc.a.z); acc.a.w = fmaf(w0, a1.y, acc.a.w);
            acc.b.x = fmaf(w0, a2.x, acc.b.x); acc.b.y = fmaf(w0, a2.y, acc.b.y);
            acc.b.z = fmaf(w0, a3.x, acc.b.z); acc.b.w = fmaf(w0, a3.y, acc.b.w);
            float2 c0 = __half22float2(*(const __half2*)&hv1.x);
            float2 c1 = __half22float2(*(const __half2*)&hv1.y);
            float2 c2 = __half22float2(*(const __half2*)&hv1.z);
            float2 c3 = __half22float2(*(const __half2*)&hv1.w);
            acc.a.x = fmaf(w1, c0.x, acc.a.x); acc.a.y = fmaf(w1, c0.y, acc.a.y);
            acc.a.z = fmaf(w1, c1.x, acc.a.z); acc.a.w = fmaf(w1, c1.y, acc.a.w);
            acc.b.x = fmaf(w1, c2.x, acc.b.x); acc.b.y = fmaf(w1, c2.y, acc.b.y);
            acc.b.z = fmaf(w1, c3.x, acc.b.z); acc.b.w = fmaf(w1, c3.y, acc.b.w);
        }
        ed = ed_next;
    }
    return acc;
}

// ---- gather1 + fused gemm2: h = relu(di*agg + b1) (regs only);
// xwh2' = di * (h @ W2) -> fp16. di from row_ptr (deg = end-start). ----
__global__ void __launch_bounds__(256, 3)
gather_gemm_kernel(const __half* __restrict__ xwh, const unsigned* __restrict__ csrw,
                   const unsigned* __restrict__ row_ptr,
                   const float* __restrict__ b1, const float* __restrict__ W2,
                   __half* __restrict__ Yh, int n) {
    __shared__ float4 Ws[64][16];  // Ws[k][j] = W2[k][4j..4j+3]
    for (int i = threadIdx.x; i < 64 * 16; i += blockDim.x)
        Ws[i >> 4][i & 15] = ((const float4*)W2)[i];
    __syncthreads();
    int lane = threadIdx.x & 63;
    int l8 = lane & 7;
    int gbase = lane & 56;
    int wid = blockIdx.x * (blockDim.x >> 6) + (threadIdx.x >> 6);
    int row = wid * 8 + (lane >> 3);
    if (row >= n) return;  // whole 8-lane group exits together (after Ws sync)
    unsigned start = row_ptr[row], end = row_ptr[row + 1];
    float di = rsqrtf((float)(end - start) + 1.0f);
    f8 acc = aggregate_row8(xwh, csrw, start, end, row, l8, gbase);
    float4 ba = ((const float4*)b1)[2 * l8];
    float4 bb = ((const float4*)b1)[2 * l8 + 1];
    float h0 = fmaxf(fmaf(di, acc.a.x, ba.x), 0.f);
    float h1 = fmaxf(fmaf(di, acc.a.y, ba.y), 0.f);
    float h2 = fmaxf(fmaf(di, acc.a.z, ba.z), 0.f);
    float h3 = fmaxf(fmaf(di, acc.a.w, ba.w), 0.f);
    float h4 = fmaxf(fmaf(di, acc.b.x, bb.x), 0.f);
    float h5 = fmaxf(fmaf(di, acc.b.y, bb.y), 0.f);
    float h6 = fmaxf(fmaf(di, acc.b.z, bb.z), 0.f);
    float h7 = fmaxf(fmaf(di, acc.b.w, bb.w), 0.f);
    // fused gemm: out[8*l8 + c] = sum_k h[k] * W2[k][8*l8+c]
    float4 o0 = make_float4(0.f, 0.f, 0.f, 0.f);
    float4 o1 = make_float4(0.f, 0.f, 0.f, 0.f);
#pragma unroll
    for (int k = 0; k < 64; ++k) {
        float comp = (k & 7) == 0 ? h0 : (k & 7) == 1 ? h1 : (k & 7) == 2 ? h2 :
                     (k & 7) == 3 ? h3 : (k & 7) == 4 ? h4 : (k & 7) == 5 ? h5 :
                     (k & 7) == 6 ? h6 : h7;
        float a = __shfl(comp, gbase + (k >> 3));
        float4 w0 = Ws[k][2 * l8];
        float4 w1 = Ws[k][2 * l8 + 1];
        o0.x = fmaf(a, w0.x, o0.x); o0.y = fmaf(a, w0.y, o0.y);
        o0.z = fmaf(a, w0.z, o0.z); o0.w = fmaf(a, w0.w, o0.w);
        o1.x = fmaf(a, w1.x, o1.x); o1.y = fmaf(a, w1.y, o1.y);
        o1.z = fmaf(a, w1.z, o1.z); o1.w = fmaf(a, w1.w, o1.w);
    }
    __half2 p0 = __floats2half2_rn(o0.x * di, o0.y * di);   // layer-2 prescale
    __half2 p1 = __floats2half2_rn(o0.z * di, o0.w * di);
    __half2 p2 = __floats2half2_rn(o1.x * di, o1.y * di);
    __half2 p3 = __floats2half2_rn(o1.z * di, o1.w * di);
    uint4 o;
    o.x = *(const unsigned*)&p0; o.y = *(const unsigned*)&p1;
    o.z = *(const unsigned*)&p2; o.w = *(const unsigned*)&p3;
    *(uint4*)(Yh + (size_t)row * 64 + 8 * l8) = o;   // 128 B contiguous: full lines
}

// ---- gather2: out = di*agg + b2 -> fp32 out (nontemporal: write-once) ----
__global__ void __launch_bounds__(256, 3)
gather_out_kernel(const __half* __restrict__ xwh, const unsigned* __restrict__ csrw,
                  const unsigned* __restrict__ row_ptr,
                  const float* __restrict__ bias, float4* __restrict__ out4, int n) {
    int lane = threadIdx.x & 63;
    int l8 = lane & 7;
    int gbase = lane & 56;
    int wid = blockIdx.x * (blockDim.x >> 6) + (threadIdx.x >> 6);
    int row = wid * 8 + (lane >> 3);
    if (row >= n) return;
    unsigned start = row_ptr[row], end = row_ptr[row + 1];
    float di = rsqrtf((float)(end - start) + 1.0f);
    f8 acc = aggregate_row8(xwh, csrw, start, end, row, l8, gbase);
    float4 ba = ((const float4*)bias)[2 * l8];
    float4 bb = ((const float4*)bias)[2 * l8 + 1];
    vfloat4 oa, ob;
    oa.x = fmaf(di, acc.a.x, ba.x); oa.y = fmaf(di, acc.a.y, ba.y);
    oa.z = fmaf(di, acc.a.z, ba.z); oa.w = fmaf(di, acc.a.w, ba.w);
    ob.x = fmaf(di, acc.b.x, bb.x); ob.y = fmaf(di, acc.b.y, bb.y);
    ob.z = fmaf(di, acc.b.z, bb.z); ob.w = fmaf(di, acc.b.w, bb.w);
    vfloat4* o4 = (vfloat4*)out4;
    __builtin_nontemporal_store(oa, &o4[(size_t)row * 16 + 2 * l8]);
    __builtin_nontemporal_store(ob, &o4[(size_t)row * 16 + 2 * l8 + 1]);
}

extern "C" void kernel_launch(void* const* d_in, const int* in_sizes, int n_in,
                              void* d_out, int out_size, void* d_ws, size_t ws_size,
                              hipStream_t stream) {
    const float* x  = (const float*)d_in[0];
    const int*   ei = (const int*)d_in[1];
    const float* W1 = (const float*)d_in[2];
    const float* b1 = (const float*)d_in[3];
    const float* W2 = (const float*)d_in[4];
    const float* b2 = (const float*)d_in[5];
    const int n = in_sizes[0] / 64;   // 50000 (packed paths require n <= 65535)
    const int e = in_sizes[1] / 2;    // 1600000
    const int* src = ei;              // edge_index[0]
    const int* dst = ei + e;          // edge_index[1]

    char* ws = (char*)d_ws;
    size_t off = 0;
    auto alloc = [&](size_t bytes) -> void* {
        void* p = ws + off;
        off = (off + bytes + 255) & ~(size_t)255;
        return p;
    };
    unsigned* rpf    = (unsigned*)alloc((size_t)(n + 1) * 4);
    unsigned* cursor = (unsigned*)alloc(256 * 4);
    unsigned short* csr = (unsigned short*)alloc(((size_t)e / 2 + 64) * 4);  // 3.2 MB, word-padded
    const int B = (n + 255) / 256;                                   // 196 buckets
    unsigned* ebuf   = (unsigned*)alloc((size_t)B * BSTRIDE * 4);    // 12.85 MB (no overlay:
    __half*   xwh1   = (__half*)alloc((size_t)n * 64 * 2);           // concurrent with gemm)
    __half*   xwh2   = (__half*)alloc((size_t)n * 64 * 2);           // 6.4 MB
    float*    outf   = (float*)d_out;

    const int nbP1 = (e + P1_EDGES - 1) / P1_EDGES;   // 391 bucket blocks
    const int gblk64 = (n + 63) / 64;                 // 782 gemm blocks (64 rows each)

    // {bucket || gemm-unscaled} -> statsfill(+dinv-scale) -> gathers
    hipMemsetAsync(cursor, 0, 256 * 4, stream);
    bucket_gemm_kernel<<<nbP1 + gblk64, 1024, 0, stream>>>(
        src, dst, cursor, ebuf, (const float4*)x, W1, xwh1, e, B, n, nbP1);
    statsfill_kernel<<<B, 1024, 0, stream>>>(ebuf, cursor, rpf, xwh1, csr, n, e);

    const int gblk32 = (n + 31) / 32;   // gathers: 8 rows/wave

    // layer 1 (+fused layer-2 gemm), then layer 2 aggregate
    gather_gemm_kernel<<<gblk32, 256, 0, stream>>>(xwh1, (const unsigned*)csr, rpf, b1, W2, xwh2, n);
    gather_out_kernel<<<gblk32, 256, 0, stream>>>(xwh2, (const unsigned*)csr, rpf, b2, (float4*)outf, n);
}